// Round 8
// baseline (196.306 us; speedup 1.0000x reference)
//
#include <hip/hip_runtime.h>
#include <hip/hip_bf16.h>

#define CDIM   1024
#define NHEADS 16
#define DHEAD  64
#define BATCH  4
#define TSEQ   2048
#define MROWS  (BATCH * TSEQ)
#define QSTR   3072                /* fused qkv row stride */
#define NEG_BIG (-1e30f)
#define MASKVAL (-3.0e38f)
#define SCALE_L2E 0.18033688011f   /* 0.125 * log2(e) */
#define DEFER_TH 11.5416f          /* 8 nats in log2 units */

typedef __attribute__((ext_vector_type(8)))  short bf16x8;
typedef __attribute__((ext_vector_type(4)))  float f32x4;
typedef __attribute__((ext_vector_type(16))) float f32x16;

__device__ __forceinline__ unsigned short f2bf(float f) {
    __hip_bfloat16 h = __float2bfloat16(f);
    return *reinterpret_cast<unsigned short*>(&h);
}
__device__ __forceinline__ unsigned int cvtpk(float a, float b) {
    unsigned r;
    asm("v_cvt_pk_bf16_f32 %0, %1, %2" : "=v"(r) : "v"(a), "v"(b));
    return r;   // lo = bf16(a), hi = bf16(b)
}
__device__ __forceinline__ float ex2(float x) {   // raw v_exp_f32 (exp2)
    float r; asm("v_exp_f32 %0, %1" : "=v"(r) : "v"(x)); return r;
}

// ---------------- x: fp32 -> bf16 (8 elems/thread) --------------------------
__global__ __launch_bounds__(256)
void cvt_x_kernel(const float* __restrict__ in, unsigned short* __restrict__ out)
{
    size_t i = (size_t)blockIdx.x * 256 + threadIdx.x;
    const float4* p = reinterpret_cast<const float4*>(in) + i * 2;
    float4 a = p[0], b = p[1];
    uint4 o;
    o.x = (unsigned)f2bf(a.x) | ((unsigned)f2bf(a.y) << 16);
    o.y = (unsigned)f2bf(a.z) | ((unsigned)f2bf(a.w) << 16);
    o.z = (unsigned)f2bf(b.x) | ((unsigned)f2bf(b.y) << 16);
    o.w = (unsigned)f2bf(b.z) | ((unsigned)f2bf(b.w) << 16);
    *reinterpret_cast<uint4*>(out + i * 8) = o;
}

// ---------------- W[K][N] fp32 -> W^T[N][K] bf16 (32x32 LDS tiles) ----------
__global__ __launch_bounds__(256)
void wt_kernel(const float* __restrict__ W0, const float* __restrict__ W1,
               const float* __restrict__ W2, const float* __restrict__ W3,
               unsigned short* __restrict__ T0, unsigned short* __restrict__ T1,
               unsigned short* __restrict__ T2, unsigned short* __restrict__ T3)
{
    const float* W; unsigned short* T;
    switch (blockIdx.z) {
        case 0:  W = W0; T = T0; break;
        case 1:  W = W1; T = T1; break;
        case 2:  W = W2; T = T2; break;
        default: W = W3; T = T3; break;
    }
    __shared__ float tile[32][33];
    const int t = threadIdx.x;
    const int r = t >> 3;
    const int c4 = (t & 7) * 4;
    const int n0 = blockIdx.x * 32, k0 = blockIdx.y * 32;
    float4 v = *reinterpret_cast<const float4*>(&W[(size_t)(k0 + r) * CDIM + n0 + c4]);
    tile[r][c4 + 0] = v.x; tile[r][c4 + 1] = v.y;
    tile[r][c4 + 2] = v.z; tile[r][c4 + 3] = v.w;
    __syncthreads();
    uint2 o;
    o.x = (unsigned)f2bf(tile[c4 + 0][r]) | ((unsigned)f2bf(tile[c4 + 1][r]) << 16);
    o.y = (unsigned)f2bf(tile[c4 + 2][r]) | ((unsigned)f2bf(tile[c4 + 3][r]) << 16);
    *reinterpret_cast<uint2*>(&T[(size_t)(n0 + r) * CDIM + k0 + c4]) = o;
}

// ---------------- bias concat [bq|bk|bv] ------------------------------------
__global__ __launch_bounds__(256)
void pack_bias(const float* __restrict__ bq, const float* __restrict__ bk,
               const float* __restrict__ bv, float* __restrict__ o)
{
    int i = blockIdx.x * 256 + threadIdx.x;   // 0..3071
    float v = (i < 1024) ? bq[i] : (i < 2048 ? bk[i - 1024] : bv[i - 2048]);
    o[i] = v;
}

// ---------------- m97-structure GEMM, BK=64 (half the barrier drains) -------
// 128x128 tile, BK=64, 4 waves (2x2). LDS rows of 128B = 8 granules of 16B;
// phys slot p at row r holds logical granule p ^ (r&7) (inverse-swizzled glds
// source + swizzled read => bank-minimal 8 words/bank both sides).
template<int OUTMODE>
__global__ __launch_bounds__(256)
void gemm_glds(const unsigned short* __restrict__ A,
               const unsigned short* __restrict__ BT,
               const float* __restrict__ bias,
               void* __restrict__ Cout, int M, int N, int K, int nScaled)
{
    __shared__ __align__(16) unsigned short As[128 * 64];   // 16KB
    __shared__ __align__(16) unsigned short Bs[128 * 64];
    const int tid = threadIdx.x;
    const int nbn = N >> 7;
    const int bid = blockIdx.x;
    const int wg  = (bid & 7) * ((int)gridDim.x >> 3) + (bid >> 3);  // XCD swizzle
    const int n0  = (wg % nbn) * 128;
    const int m0  = (wg / nbn) * 128;

    const int lane = tid & 63, w = tid >> 6;
    const int wr = w >> 1, wc = w & 1;
    const int lj = lane & 15, lg = lane >> 4;
    const int srow = w * 8 + (lane >> 3);               // row within 32-row round
    const int gsw  = 8 * ((lane & 7) ^ (lane >> 3));    // src granule (elements)

    char* AsB = (char*)As;
    char* BsB = (char*)Bs;

    f32x4 acc[4][4];
    #pragma unroll
    for (int i = 0; i < 4; ++i)
        #pragma unroll
        for (int j = 0; j < 4; ++j) acc[i][j] = f32x4{0.f, 0.f, 0.f, 0.f};

    for (int k0 = 0; k0 < K; k0 += 64) {
        __syncthreads();
        #pragma unroll
        for (int ra = 0; ra < 4; ++ra) {
            const int r = ra * 32 + srow;
            __builtin_amdgcn_global_load_lds(
                (const __attribute__((address_space(1))) void*)(A + (size_t)(m0 + r) * K + k0 + gsw),
                (__attribute__((address_space(3))) void*)(AsB + ra * 4096 + w * 1024),
                16, 0, 0);
            __builtin_amdgcn_global_load_lds(
                (const __attribute__((address_space(1))) void*)(BT + (size_t)(n0 + r) * K + k0 + gsw),
                (__attribute__((address_space(3))) void*)(BsB + ra * 4096 + w * 1024),
                16, 0, 0);
        }
        __syncthreads();
        #pragma unroll
        for (int ks = 0; ks < 2; ++ks) {
            bf16x8 af[4], bfr[4];
            #pragma unroll
            for (int i = 0; i < 4; ++i) {
                const int r = wr * 64 + i * 16 + lj;
                af[i] = *reinterpret_cast<const bf16x8*>(
                    AsB + r * 128 + (((ks * 4 + lg) ^ (lj & 7)) * 16));
            }
            #pragma unroll
            for (int j = 0; j < 4; ++j) {
                const int r = wc * 64 + j * 16 + lj;
                bfr[j] = *reinterpret_cast<const bf16x8*>(
                    BsB + r * 128 + (((ks * 4 + lg) ^ (lj & 7)) * 16));
            }
            #pragma unroll
            for (int i = 0; i < 4; ++i)
                #pragma unroll
                for (int j = 0; j < 4; ++j)
                    acc[i][j] = __builtin_amdgcn_mfma_f32_16x16x32_bf16(af[i], bfr[j], acc[i][j], 0, 0, 0);
        }
    }

    const float sc = (n0 < nScaled) ? SCALE_L2E : 1.0f;
    float bcol[4];
    #pragma unroll
    for (int j = 0; j < 4; ++j) bcol[j] = bias[n0 + wc * 64 + j * 16 + lj];

    #pragma unroll
    for (int i = 0; i < 4; ++i) {
        #pragma unroll
        for (int r4 = 0; r4 < 4; ++r4) {
            const int row = m0 + wr * 64 + i * 16 + lg * 4 + r4;
            #pragma unroll
            for (int j = 0; j < 4; ++j) {
                const int col = n0 + wc * 64 + j * 16 + lj;
                float v = (acc[i][j][r4] + bcol[j]) * sc;
                if (OUTMODE == 0)
                    reinterpret_cast<unsigned short*>(Cout)[(size_t)row * N + col] = f2bf(v);
                else
                    reinterpret_cast<float*>(Cout)[(size_t)row * N + col] = v;
            }
        }
    }
}

// ---------------- MFMA flash attention, split-KV x2 -------------------------
// 512 blocks x 512 thr = 8 waves: group g (waves 4g..4g+3) handles KV-tiles
// kt = 2i+g for the SAME 128-row q-tile; per-group LDS + online-softmax state;
// per-lane merge through the freed staging LDS at q-tile end. ktend always
// even => both groups run qtile+1 iterations (uniform barriers).
// Doubles resident waves/SIMD (2 -> 4) to hide latency.
#define PV_STEP(m, T, rb) { \
    unsigned int w01 = cvtpk(T[(rb)+0], T[(rb)+1]); \
    unsigned int w23 = cvtpk(T[(rb)+2], T[(rb)+3]); \
    unsigned int w45 = cvtpk(T[(rb)+4], T[(rb)+5]); \
    unsigned int w67 = cvtpk(T[(rb)+6], T[(rb)+7]); \
    asm("v_permlane32_swap_b32 %0, %1" : "+v"(w01), "+v"(w45)); \
    asm("v_permlane32_swap_b32 %0, %1" : "+v"(w23), "+v"(w67)); \
    union { unsigned int u[4]; bf16x8 v; } pa; \
    pa.u[0] = w01; pa.u[1] = w23; pa.u[2] = w45; pa.u[3] = w67; \
    const int voff = (32 * (m) + 16 * hi) ^ lqswz; \
    bf16x8 va = *reinterpret_cast<const bf16x8*>(VTB + lq * 128 + voff); \
    bf16x8 vb = *reinterpret_cast<const bf16x8*>(VTB + (lq + 32) * 128 + voff); \
    y0 = __builtin_amdgcn_mfma_f32_32x32x16_bf16(va, pa.v, y0, 0, 0, 0); \
    y1 = __builtin_amdgcn_mfma_f32_32x32x16_bf16(vb, pa.v, y1, 0, 0, 0); \
}

__global__ __launch_bounds__(512, 4)
void attn_mfma7(const unsigned short* __restrict__ QKV, unsigned short* __restrict__ Yb)
{
    __shared__ __align__(16) char ldsG[2][16384];        // per-group K 8KB | V^T 8KB
    __shared__ unsigned short Ysc[4][32 * 72];           // epilogue + (m,l) scratch

    const int tid = threadIdx.x, lane = tid & 63, wid = tid >> 6;
    const int grp = wid >> 2, cw = wid & 3;
    const int lq = lane & 31, hi = lane >> 5;
    const int lqswz = (lq & 7) << 4;
    const int tg = tid & 255;                            // thread within group

    // XCD-grouped decomposition (R5): id%8 == hb%8 -> same (h,b) shares an XCD
    const int id  = blockIdx.x;
    const int kk  = id >> 3;
    const int hb  = (id & 7) + 8 * (kk >> 3);
    const int pair = kk & 7;
    const int h = hb & 15, bz = hb >> 4;

    const size_t rowbase = (size_t)bz * TSEQ;
    const int hq = h * DHEAD, hk = 1024 + h * DHEAD, hv = 2048 + h * DHEAD;
    char* KsB = &ldsG[grp][0];
    char* VTB = &ldsG[grp][8192];

    // staging thread mapping (within group, constant per thread)
    const int krow = tg >> 3;            // K rows krow, krow+32
    const int kcol8 = (tg & 7) * 8;
    const int kswz = ((tg & 7) * 16) ^ ((krow & 7) << 4);
    const int vk2  = 2 * (tg & 31);      // V key-pair
    const int vdg  = (tg >> 5) * 8;      // V d-group
    const int vkb  = vk2 * 2;            // byte offset of pair

    for (int iter = 0; iter < 2; ++iter) {
        const int qtile = iter ? (15 - pair) : pair;
        const int q0 = qtile * 128;
        const int wq = q0 + cw * 32;

        bf16x8 qf[4];                            // Q^T B-frags: d = 16s + 8hi + j
        {
            const unsigned short* qp = QKV + (rowbase + wq + lq) * QSTR + hq + hi * 8;
            #pragma unroll
            for (int s = 0; s < 4; ++s)
                qf[s] = *reinterpret_cast<const bf16x8*>(qp + s * 16);
        }
        f32x16 y0, y1;
        #pragma unroll
        for (int r = 0; r < 16; ++r) { y0[r] = 0.f; y1[r] = 0.f; }
        float mrow = NEG_BIG, lrow = 0.f;

        const int nIt = qtile + 1;               // per-group iterations

        // prefetch this group's tile (kt = grp) into registers
        uint4 kr0, kr1, vr0, vr1;
        {
            const unsigned short* kp = QKV + (rowbase + grp * 64 + krow) * QSTR + hk + kcol8;
            kr0 = *reinterpret_cast<const uint4*>(kp);
            kr1 = *reinterpret_cast<const uint4*>(kp + 32 * QSTR);
            const unsigned short* vp = QKV + (rowbase + grp * 64 + vk2) * QSTR + hv + vdg;
            vr0 = *reinterpret_cast<const uint4*>(vp);
            vr1 = *reinterpret_cast<const uint4*>(vp + QSTR);
        }

        for (int i = 0; i < nIt; ++i) {
            const int ktg = 2 * i + grp;
            __syncthreads();                     // previous tile's consumers done
            // ---- write prefetched regs -> group LDS (K swizzled, V^T perm-packed)
            *reinterpret_cast<uint4*>(KsB + krow * 128 + kswz) = kr0;
            *reinterpret_cast<uint4*>(KsB + (krow + 32) * 128 + kswz) = kr1;
            {
                unsigned pe, po;
                pe = __builtin_amdgcn_perm(vr1.x, vr0.x, 0x05040100u);
                po = __builtin_amdgcn_perm(vr1.x, vr0.x, 0x07060302u);
                *reinterpret_cast<unsigned*>(VTB + (vdg + 0) * 128 + (vkb ^ 0x00)) = pe;
                *reinterpret_cast<unsigned*>(VTB + (vdg + 1) * 128 + (vkb ^ 0x10)) = po;
                pe = __builtin_amdgcn_perm(vr1.y, vr0.y, 0x05040100u);
                po = __builtin_amdgcn_perm(vr1.y, vr0.y, 0x07060302u);
                *reinterpret_cast<unsigned*>(VTB + (vdg + 2) * 128 + (vkb ^ 0x20)) = pe;
                *reinterpret_cast<unsigned*>(VTB + (vdg + 3) * 128 + (vkb ^ 0x30)) = po;
                pe = __builtin_amdgcn_perm(vr1.z, vr0.z, 0x05040100u);
                po = __builtin_amdgcn_perm(vr1.z, vr0.z, 0x07060302u);
                *reinterpret_cast<unsigned*>(VTB + (vdg + 4) * 128 + (vkb ^ 0x40)) = pe;
                *reinterpret_cast<unsigned*>(VTB + (vdg + 5) * 128 + (vkb ^ 0x50)) = po;
                pe = __builtin_amdgcn_perm(vr1.w, vr0.w, 0x05040100u);
                po = __builtin_amdgcn_perm(vr1.w, vr0.w, 0x07060302u);
                *reinterpret_cast<unsigned*>(VTB + (vdg + 6) * 128 + (vkb ^ 0x60)) = pe;
                *reinterpret_cast<unsigned*>(VTB + (vdg + 7) * 128 + (vkb ^ 0x70)) = po;
            }
            __syncthreads();                     // LDS tile ready

            // ---- issue next group-tile's global loads (hide under compute)
            if (i + 1 < nIt) {
                const int ktn = 2 * (i + 1) + grp;
                const unsigned short* kp = QKV + (rowbase + ktn * 64 + krow) * QSTR + hk + kcol8;
                kr0 = *reinterpret_cast<const uint4*>(kp);
                kr1 = *reinterpret_cast<const uint4*>(kp + 32 * QSTR);
                const unsigned short* vp = QKV + (rowbase + ktn * 64 + vk2) * QSTR + hv + vdg;
                vr0 = *reinterpret_cast<const uint4*>(vp);
                vr1 = *reinterpret_cast<const uint4*>(vp + QSTR);
            }

            if (ktg * 64 > wq + 31) continue;    // tile above diagonal for this wave

            // ---- S^T = K Q^T (8 mfma 32x32x16); scale pre-folded into Q
            f32x16 s0, s1;
            #pragma unroll
            for (int r = 0; r < 16; ++r) { s0[r] = 0.f; s1[r] = 0.f; }
            #pragma unroll
            for (int s = 0; s < 4; ++s) {
                const int off = (s * 32 + hi * 16) ^ lqswz;
                bf16x8 k0 = *reinterpret_cast<const bf16x8*>(KsB + lq * 128 + off);
                bf16x8 k1 = *reinterpret_cast<const bf16x8*>(KsB + (lq + 32) * 128 + off);
                s0 = __builtin_amdgcn_mfma_f32_32x32x16_bf16(k0, qf[s], s0, 0, 0, 0);
                s1 = __builtin_amdgcn_mfma_f32_32x32x16_bf16(k1, qf[s], s1, 0, 0, 0);
            }

            // ---- causal mask (diagonal tiles only)
            const bool diag = (ktg * 64 + 63) > wq;
            if (diag) {
                const int q_own = wq + lq;
                #pragma unroll
                for (int r = 0; r < 16; ++r) {
                    const int kl = ktg * 64 + (r & 3) + 8 * (r >> 2) + 4 * hi;
                    if (kl > q_own) s0[r] = MASKVAL;
                    if (kl + 32 > q_own) s1[r] = MASKVAL;
                }
            }

            // ---- tree row max + pair exchange
            float t8[8];
            #pragma unroll
            for (int r = 0; r < 8; ++r)
                t8[r] = fmaxf(fmaxf(s0[r], s0[r + 8]), fmaxf(s1[r], s1[r + 8]));
            #pragma unroll
            for (int r = 0; r < 4; ++r) t8[r] = fmaxf(t8[r], t8[r + 4]);
            float pm = fmaxf(fmaxf(t8[0], t8[1]), fmaxf(t8[2], t8[3]));
            pm = fmaxf(pm, __shfl_xor(pm, 32));

            // ---- defer-max rescale (T13)
            if (__any(pm > mrow + DEFER_TH)) {
                const float mnew = fmaxf(mrow, pm);
                const float alpha = ex2(mrow - mnew);
                #pragma unroll
                for (int r = 0; r < 16; ++r) { y0[r] *= alpha; y1[r] *= alpha; }
                lrow *= alpha;
                mrow = mnew;
            }
            // ---- exp2 + tree row sum
            #pragma unroll
            for (int r = 0; r < 16; ++r) {
                s0[r] = ex2(s0[r] - mrow);
                s1[r] = ex2(s1[r] - mrow);
            }
            float a8[8];
            #pragma unroll
            for (int r = 0; r < 8; ++r) a8[r] = (s0[r] + s0[r + 8]) + (s1[r] + s1[r + 8]);
            #pragma unroll
            for (int r = 0; r < 4; ++r) a8[r] += a8[r + 4];
            float sum = (a8[0] + a8[1]) + (a8[2] + a8[3]);
            sum += __shfl_xor(sum, 32);
            lrow += sum;

            // ---- Y^T += V^T P^T (8 mfma)
            PV_STEP(0, s0, 0)
            PV_STEP(1, s0, 8)
            PV_STEP(2, s1, 0)
            PV_STEP(3, s1, 8)
        }

        // ---- merge group 1 -> group 0 (per-lane, via freed staging LDS)
        __syncthreads();                         // all compute done, ldsG free
        if (grp == 1) {
            char* mb = (char*)ldsG + cw * 8192;
            #pragma unroll
            for (int r = 0; r < 16; ++r) {
                *reinterpret_cast<float*>(mb + r * 256 + lane * 4) = y0[r];
                *reinterpret_cast<float*>(mb + 4096 + r * 256 + lane * 4) = y1[r];
            }
            float2* ml = reinterpret_cast<float2*>(&Ysc[cw][0]);
            ml[lane] = float2{mrow, lrow};
        }
        __syncthreads();
        if (grp == 0) {
            char* mb = (char*)ldsG + cw * 8192;
            const float2 ml = reinterpret_cast<const float2*>(&Ysc[cw][0])[lane];
            const float mN = fmaxf(mrow, ml.x);
            const float a0 = ex2(mrow - mN), a1 = ex2(ml.x - mN);
            lrow = lrow * a0 + ml.y * a1;
            mrow = mN;
            #pragma unroll
            for (int r = 0; r < 16; ++r) {
                float z0 = *reinterpret_cast<const float*>(mb + r * 256 + lane * 4);
                float z1 = *reinterpret_cast<const float*>(mb + 4096 + r * 256 + lane * 4);
                y0[r] = y0[r] * a0 + z0 * a1;
                y1[r] = y1[r] * a0 + z1 * a1;
            }
            // ---- epilogue: normalize, transpose via per-wave LDS, coalesced store
            const float inv = 1.f / lrow;
            char* ysb = (char*)&Ysc[cw][0];
            #pragma unroll
            for (int t = 0; t < 8; ++t) {
                const int dl = ((2 * t) & 3) + 8 * (t >> 1) + 4 * hi;
                unsigned int wa = cvtpk(y0[2 * t] * inv, y0[2 * t + 1] * inv);
                unsigned int wb = cvtpk(y1[2 * t] * inv, y1[2 * t + 1] * inv);
                *reinterpret_cast<unsigned int*>(ysb + lq * 144 + dl * 2) = wa;
                *reinterpret_cast<unsigned int*>(ysb + lq * 144 + (dl + 32) * 2) = wb;
            }
            #pragma unroll
            for (int u = 0; u < 4; ++u) {
                const int rr = lane >> 1, ch = (lane & 1) + 2 * u;
                uint4 val = *reinterpret_cast<const uint4*>(ysb + rr * 144 + ch * 16);
                *reinterpret_cast<uint4*>(Yb + (rowbase + q0 + cw * 32 + rr) * CDIM + h * DHEAD + ch * 8) = val;
            }
        }
        // next iter's loop-top __syncthreads separates merge reads from staging
    }
}

// ---------------------------------------------------------------------------
extern "C" void kernel_launch(void* const* d_in, const int* in_sizes, int n_in,
                              void* d_out, int out_size, void* d_ws, size_t ws_size,
                              hipStream_t stream)
{
    const float* x  = (const float*)d_in[0];
    const float* Wk = (const float*)d_in[1];
    const float* bk = (const float*)d_in[2];
    const float* Wq = (const float*)d_in[3];
    const float* bq = (const float*)d_in[4];
    const float* Wv = (const float*)d_in[5];
    const float* bv = (const float*)d_in[6];
    const float* Wp = (const float*)d_in[7];
    const float* bp = (const float*)d_in[8];

    const size_t xe = (size_t)MROWS * CDIM;   // 8,388,608
    const size_t we = (size_t)CDIM * CDIM;    // 1,048,576
    unsigned short* xb    = (unsigned short*)d_ws;
    unsigned short* wqkvt = xb + xe;          // [3072][1024] = Wq^T|Wk^T|Wv^T
    unsigned short* wpt   = wqkvt + 3 * we;
    unsigned short* qkv   = wpt + we;         // [8192][3072] bf16
    unsigned short* ab    = qkv + (size_t)MROWS * QSTR;
    float*          bias3 = (float*)(ab + xe);

    cvt_x_kernel<<<(int)(xe / 8 / 256), 256, 0, stream>>>(x, xb);
    wt_kernel<<<dim3(32, 32, 4), 256, 0, stream>>>(
        Wq, Wk, Wv, Wp, wqkvt, wqkvt + we, wqkvt + 2 * we, wpt);
    pack_bias<<<12, 256, 0, stream>>>(bq, bk, bv, bias3);

    // fused QKV projection: [8192,1024] @ [1024,3072] + bias (q cols scaled)
    gemm_glds<0><<<24 * 64, 256, 0, stream>>>(xb, wqkvt, bias3, qkv,
                                              MROWS, QSTR, CDIM, 1024);

    attn_mfma7<<<512, 512, 0, stream>>>(qkv, ab);

    // output projection -> fp32
    gemm_glds<1><<<8 * 64, 256, 0, stream>>>(ab, wpt, bp, d_out,
                                             MROWS, CDIM, CDIM, 0);
}

// Round 9
// 169.784 us; speedup vs baseline: 1.1562x; 1.1562x over previous
//
#include <hip/hip_runtime.h>
#include <hip/hip_bf16.h>

#define CDIM   1024
#define NHEADS 16
#define DHEAD  64
#define BATCH  4
#define TSEQ   2048
#define MROWS  (BATCH * TSEQ)
#define QSTR   3072                /* fused qkv row stride */
#define NEG_BIG (-1e30f)
#define MASKVAL (-3.0e38f)
#define SCALE_L2E 0.18033688011f   /* 0.125 * log2(e) */
#define DEFER_TH 11.5416f          /* 8 nats in log2 units */

typedef __attribute__((ext_vector_type(8)))  short bf16x8;
typedef __attribute__((ext_vector_type(4)))  float f32x4;
typedef __attribute__((ext_vector_type(16))) float f32x16;

__device__ __forceinline__ unsigned short f2bf(float f) {
    __hip_bfloat16 h = __float2bfloat16(f);
    return *reinterpret_cast<unsigned short*>(&h);
}
__device__ __forceinline__ unsigned int cvtpk(float a, float b) {
    unsigned r;
    asm("v_cvt_pk_bf16_f32 %0, %1, %2" : "=v"(r) : "v"(a), "v"(b));
    return r;   // lo = bf16(a), hi = bf16(b)
}
__device__ __forceinline__ float ex2(float x) {   // raw v_exp_f32 (exp2)
    float r; asm("v_exp_f32 %0, %1" : "=v"(r) : "v"(x)); return r;
}

// ---------------- x: fp32 -> bf16 (8 elems/thread) --------------------------
__global__ __launch_bounds__(256)
void cvt_x_kernel(const float* __restrict__ in, unsigned short* __restrict__ out)
{
    size_t i = (size_t)blockIdx.x * 256 + threadIdx.x;
    const float4* p = reinterpret_cast<const float4*>(in) + i * 2;
    float4 a = p[0], b = p[1];
    uint4 o;
    o.x = (unsigned)f2bf(a.x) | ((unsigned)f2bf(a.y) << 16);
    o.y = (unsigned)f2bf(a.z) | ((unsigned)f2bf(a.w) << 16);
    o.z = (unsigned)f2bf(b.x) | ((unsigned)f2bf(b.y) << 16);
    o.w = (unsigned)f2bf(b.z) | ((unsigned)f2bf(b.w) << 16);
    *reinterpret_cast<uint4*>(out + i * 8) = o;
}

// ---------------- W[K][N] fp32 -> W^T[N][K] bf16 (32x32 LDS tiles) ----------
__global__ __launch_bounds__(256)
void wt_kernel(const float* __restrict__ W0, const float* __restrict__ W1,
               const float* __restrict__ W2, const float* __restrict__ W3,
               unsigned short* __restrict__ T0, unsigned short* __restrict__ T1,
               unsigned short* __restrict__ T2, unsigned short* __restrict__ T3)
{
    const float* W; unsigned short* T;
    switch (blockIdx.z) {
        case 0:  W = W0; T = T0; break;
        case 1:  W = W1; T = T1; break;
        case 2:  W = W2; T = T2; break;
        default: W = W3; T = T3; break;
    }
    __shared__ float tile[32][33];
    const int t = threadIdx.x;
    const int r = t >> 3;
    const int c4 = (t & 7) * 4;
    const int n0 = blockIdx.x * 32, k0 = blockIdx.y * 32;
    float4 v = *reinterpret_cast<const float4*>(&W[(size_t)(k0 + r) * CDIM + n0 + c4]);
    tile[r][c4 + 0] = v.x; tile[r][c4 + 1] = v.y;
    tile[r][c4 + 2] = v.z; tile[r][c4 + 3] = v.w;
    __syncthreads();
    uint2 o;
    o.x = (unsigned)f2bf(tile[c4 + 0][r]) | ((unsigned)f2bf(tile[c4 + 1][r]) << 16);
    o.y = (unsigned)f2bf(tile[c4 + 2][r]) | ((unsigned)f2bf(tile[c4 + 3][r]) << 16);
    *reinterpret_cast<uint2*>(&T[(size_t)(n0 + r) * CDIM + k0 + c4]) = o;
}

// ---------------- bias concat [bq|bk|bv] ------------------------------------
__global__ __launch_bounds__(256)
void pack_bias(const float* __restrict__ bq, const float* __restrict__ bk,
               const float* __restrict__ bv, float* __restrict__ o)
{
    int i = blockIdx.x * 256 + threadIdx.x;   // 0..3071
    float v = (i < 1024) ? bq[i] : (i < 2048 ? bk[i - 1024] : bv[i - 2048]);
    o[i] = v;
}

// ---------------- m97-structure GEMM, BK=64 (half the barrier drains) -------
// 128x128 tile, BK=64, 4 waves (2x2). LDS rows of 128B = 8 granules of 16B;
// phys slot p at row r holds logical granule p ^ (r&7) (inverse-swizzled glds
// source + swizzled read => bank-minimal 8 words/bank both sides).
// R8-verified: QKV proj ~62us (was 80.5 at BK=32).
template<int OUTMODE>
__global__ __launch_bounds__(256)
void gemm_glds(const unsigned short* __restrict__ A,
               const unsigned short* __restrict__ BT,
               const float* __restrict__ bias,
               void* __restrict__ Cout, int M, int N, int K, int nScaled)
{
    __shared__ __align__(16) unsigned short As[128 * 64];   // 16KB
    __shared__ __align__(16) unsigned short Bs[128 * 64];
    const int tid = threadIdx.x;
    const int nbn = N >> 7;
    const int bid = blockIdx.x;
    const int wg  = (bid & 7) * ((int)gridDim.x >> 3) + (bid >> 3);  // XCD swizzle
    const int n0  = (wg % nbn) * 128;
    const int m0  = (wg / nbn) * 128;

    const int lane = tid & 63, w = tid >> 6;
    const int wr = w >> 1, wc = w & 1;
    const int lj = lane & 15, lg = lane >> 4;
    const int srow = w * 8 + (lane >> 3);               // row within 32-row round
    const int gsw  = 8 * ((lane & 7) ^ (lane >> 3));    // src granule (elements)

    char* AsB = (char*)As;
    char* BsB = (char*)Bs;

    f32x4 acc[4][4];
    #pragma unroll
    for (int i = 0; i < 4; ++i)
        #pragma unroll
        for (int j = 0; j < 4; ++j) acc[i][j] = f32x4{0.f, 0.f, 0.f, 0.f};

    for (int k0 = 0; k0 < K; k0 += 64) {
        __syncthreads();
        #pragma unroll
        for (int ra = 0; ra < 4; ++ra) {
            const int r = ra * 32 + srow;
            __builtin_amdgcn_global_load_lds(
                (const __attribute__((address_space(1))) void*)(A + (size_t)(m0 + r) * K + k0 + gsw),
                (__attribute__((address_space(3))) void*)(AsB + ra * 4096 + w * 1024),
                16, 0, 0);
            __builtin_amdgcn_global_load_lds(
                (const __attribute__((address_space(1))) void*)(BT + (size_t)(n0 + r) * K + k0 + gsw),
                (__attribute__((address_space(3))) void*)(BsB + ra * 4096 + w * 1024),
                16, 0, 0);
        }
        __syncthreads();
        #pragma unroll
        for (int ks = 0; ks < 2; ++ks) {
            bf16x8 af[4], bfr[4];
            #pragma unroll
            for (int i = 0; i < 4; ++i) {
                const int r = wr * 64 + i * 16 + lj;
                af[i] = *reinterpret_cast<const bf16x8*>(
                    AsB + r * 128 + (((ks * 4 + lg) ^ (lj & 7)) * 16));
            }
            #pragma unroll
            for (int j = 0; j < 4; ++j) {
                const int r = wc * 64 + j * 16 + lj;
                bfr[j] = *reinterpret_cast<const bf16x8*>(
                    BsB + r * 128 + (((ks * 4 + lg) ^ (lj & 7)) * 16));
            }
            #pragma unroll
            for (int i = 0; i < 4; ++i)
                #pragma unroll
                for (int j = 0; j < 4; ++j)
                    acc[i][j] = __builtin_amdgcn_mfma_f32_16x16x32_bf16(af[i], bfr[j], acc[i][j], 0, 0, 0);
        }
    }

    const float sc = (n0 < nScaled) ? SCALE_L2E : 1.0f;
    float bcol[4];
    #pragma unroll
    for (int j = 0; j < 4; ++j) bcol[j] = bias[n0 + wc * 64 + j * 16 + lj];

    #pragma unroll
    for (int i = 0; i < 4; ++i) {
        #pragma unroll
        for (int r4 = 0; r4 < 4; ++r4) {
            const int row = m0 + wr * 64 + i * 16 + lg * 4 + r4;
            #pragma unroll
            for (int j = 0; j < 4; ++j) {
                const int col = n0 + wc * 64 + j * 16 + lj;
                float v = (acc[i][j][r4] + bcol[j]) * sc;
                if (OUTMODE == 0)
                    reinterpret_cast<unsigned short*>(Cout)[(size_t)row * N + col] = f2bf(v);
                else
                    reinterpret_cast<float*>(Cout)[(size_t)row * N + col] = v;
            }
        }
    }
}

// ---------------- MFMA flash attention (R7-verified: 80us, VGPR 124) --------
// 512 blocks, 4 waves x 32 q-rows = 128-row q-tile; balanced pair (p, 15-p)
// sequentially (uniform 34 KV-iterations). XCD-grouped id mapping (R5).
// KV single-LDS-buffer, reg prefetch of kt+1. cvt_pk P-pack, tree reductions,
// raw v_exp, v_perm V-pack. DO NOT add __launch_bounds__ min-waves: R8's
// (512,4) variant spilled to scratch (VGPR 64, WRITE_SIZE 119MB, +35% dur).
#define PV_STEP(m, T, rb) { \
    unsigned int w01 = cvtpk(T[(rb)+0], T[(rb)+1]); \
    unsigned int w23 = cvtpk(T[(rb)+2], T[(rb)+3]); \
    unsigned int w45 = cvtpk(T[(rb)+4], T[(rb)+5]); \
    unsigned int w67 = cvtpk(T[(rb)+6], T[(rb)+7]); \
    asm("v_permlane32_swap_b32 %0, %1" : "+v"(w01), "+v"(w45)); \
    asm("v_permlane32_swap_b32 %0, %1" : "+v"(w23), "+v"(w67)); \
    union { unsigned int u[4]; bf16x8 v; } pa; \
    pa.u[0] = w01; pa.u[1] = w23; pa.u[2] = w45; pa.u[3] = w67; \
    const int voff = (32 * (m) + 16 * hi) ^ lqswz; \
    bf16x8 va = *reinterpret_cast<const bf16x8*>(VTB + lq * 128 + voff); \
    bf16x8 vb = *reinterpret_cast<const bf16x8*>(VTB + (lq + 32) * 128 + voff); \
    y0 = __builtin_amdgcn_mfma_f32_32x32x16_bf16(va, pa.v, y0, 0, 0, 0); \
    y1 = __builtin_amdgcn_mfma_f32_32x32x16_bf16(vb, pa.v, y1, 0, 0, 0); \
}

__global__ __launch_bounds__(256)
void attn_mfma6(const unsigned short* __restrict__ QKV, unsigned short* __restrict__ Yb)
{
    __shared__ unsigned short Ks[64 * 64];    // [key][d], swizzled
    __shared__ unsigned short VTs[64 * 64];   // [d][key], swizzled
    __shared__ unsigned short Ysc[4][32 * 72];// per-wave [q][d], 144B stride

    const int tid = threadIdx.x, lane = tid & 63, wid = tid >> 6;
    const int lq = lane & 31, hi = lane >> 5;
    const int lqswz = (lq & 7) << 4;

    // XCD-grouped decomposition: id%8 == hb%8 -> same (h,b) shares an XCD
    const int id  = blockIdx.x;
    const int kk  = id >> 3;
    const int hb  = (id & 7) + 8 * (kk >> 3);
    const int pair = kk & 7;
    const int h = hb & 15, bz = hb >> 4;

    const size_t rowbase = (size_t)bz * TSEQ;
    const int hq = h * DHEAD, hk = 1024 + h * DHEAD, hv = 2048 + h * DHEAD;
    char* KsB = (char*)Ks;
    char* VTB = (char*)VTs;

    // staging thread mapping (constant per thread)
    const int krow = tid >> 3;           // K rows krow, krow+32
    const int kswz = ((tid & 7) * 16) ^ ((krow & 7) << 4);
    const int vk2  = 2 * (tid & 31);     // V key-pair
    const int vdg  = (tid >> 5) * 8;     // V d-group
    const int vkb  = vk2 * 2;            // byte offset of pair

    for (int iter = 0; iter < 2; ++iter) {
        const int qtile = iter ? (15 - pair) : pair;
        const int q0 = qtile * 128;
        const int wq = q0 + wid * 32;

        bf16x8 qf[4];                            // Q^T B-frags: d = 16s + 8hi + j
        {
            const unsigned short* qp = QKV + (rowbase + wq + lq) * QSTR + hq + hi * 8;
            #pragma unroll
            for (int s = 0; s < 4; ++s)
                qf[s] = *reinterpret_cast<const bf16x8*>(qp + s * 16);
        }
        f32x16 y0, y1;                           // Y^T tiles: d 0..31 / 32..63
        #pragma unroll
        for (int r = 0; r < 16; ++r) { y0[r] = 0.f; y1[r] = 0.f; }
        float mrow = NEG_BIG, lrow = 0.f;

        const int ktend = 2 * qtile + 2;

        // prefetch tile 0 into registers
        uint4 kr0, kr1, vr0, vr1;
        {
            const unsigned short* kp = QKV + (rowbase + krow) * QSTR + hk + (tid & 7) * 8;
            kr0 = *reinterpret_cast<const uint4*>(kp);
            kr1 = *reinterpret_cast<const uint4*>(kp + 32 * QSTR);
            const unsigned short* vp = QKV + (rowbase + vk2) * QSTR + hv + vdg;
            vr0 = *reinterpret_cast<const uint4*>(vp);
            vr1 = *reinterpret_cast<const uint4*>(vp + QSTR);
        }

        for (int kt = 0; kt < ktend; ++kt) {
            __syncthreads();                     // previous tile's consumers done
            // ---- write prefetched regs -> LDS (K swizzled, V^T perm-packed)
            *reinterpret_cast<uint4*>(KsB + krow * 128 + kswz) = kr0;
            *reinterpret_cast<uint4*>(KsB + (krow + 32) * 128 + kswz) = kr1;
            {
                unsigned pe, po;
                pe = __builtin_amdgcn_perm(vr1.x, vr0.x, 0x05040100u);
                po = __builtin_amdgcn_perm(vr1.x, vr0.x, 0x07060302u);
                *reinterpret_cast<unsigned*>(VTB + (vdg + 0) * 128 + (vkb ^ 0x00)) = pe;
                *reinterpret_cast<unsigned*>(VTB + (vdg + 1) * 128 + (vkb ^ 0x10)) = po;
                pe = __builtin_amdgcn_perm(vr1.y, vr0.y, 0x05040100u);
                po = __builtin_amdgcn_perm(vr1.y, vr0.y, 0x07060302u);
                *reinterpret_cast<unsigned*>(VTB + (vdg + 2) * 128 + (vkb ^ 0x20)) = pe;
                *reinterpret_cast<unsigned*>(VTB + (vdg + 3) * 128 + (vkb ^ 0x30)) = po;
                pe = __builtin_amdgcn_perm(vr1.z, vr0.z, 0x05040100u);
                po = __builtin_amdgcn_perm(vr1.z, vr0.z, 0x07060302u);
                *reinterpret_cast<unsigned*>(VTB + (vdg + 4) * 128 + (vkb ^ 0x40)) = pe;
                *reinterpret_cast<unsigned*>(VTB + (vdg + 5) * 128 + (vkb ^ 0x50)) = po;
                pe = __builtin_amdgcn_perm(vr1.w, vr0.w, 0x05040100u);
                po = __builtin_amdgcn_perm(vr1.w, vr0.w, 0x07060302u);
                *reinterpret_cast<unsigned*>(VTB + (vdg + 6) * 128 + (vkb ^ 0x60)) = pe;
                *reinterpret_cast<unsigned*>(VTB + (vdg + 7) * 128 + (vkb ^ 0x70)) = po;
            }
            __syncthreads();                     // LDS tile ready

            // ---- issue next tile's global loads (latency hides under compute)
            if (kt + 1 < ktend) {
                const unsigned short* kp = QKV + (rowbase + (kt + 1) * 64 + krow) * QSTR + hk + (tid & 7) * 8;
                kr0 = *reinterpret_cast<const uint4*>(kp);
                kr1 = *reinterpret_cast<const uint4*>(kp + 32 * QSTR);
                const unsigned short* vp = QKV + (rowbase + (kt + 1) * 64 + vk2) * QSTR + hv + vdg;
                vr0 = *reinterpret_cast<const uint4*>(vp);
                vr1 = *reinterpret_cast<const uint4*>(vp + QSTR);
            }

            if (kt * 64 > wq + 31) continue;     // tile above diagonal for this wave

            // ---- S^T = K Q^T (8 mfma 32x32x16); scale pre-folded into Q
            f32x16 s0, s1;
            #pragma unroll
            for (int r = 0; r < 16; ++r) { s0[r] = 0.f; s1[r] = 0.f; }
            #pragma unroll
            for (int s = 0; s < 4; ++s) {
                const int off = (s * 32 + hi * 16) ^ lqswz;
                bf16x8 k0 = *reinterpret_cast<const bf16x8*>(KsB + lq * 128 + off);
                bf16x8 k1 = *reinterpret_cast<const bf16x8*>(KsB + (lq + 32) * 128 + off);
                s0 = __builtin_amdgcn_mfma_f32_32x32x16_bf16(k0, qf[s], s0, 0, 0, 0);
                s1 = __builtin_amdgcn_mfma_f32_32x32x16_bf16(k1, qf[s], s1, 0, 0, 0);
            }

            // ---- causal mask (diagonal tiles only)
            const bool diag = (kt * 64 + 63) > wq;
            if (diag) {
                const int q_own = wq + lq;
                #pragma unroll
                for (int r = 0; r < 16; ++r) {
                    const int kl = kt * 64 + (r & 3) + 8 * (r >> 2) + 4 * hi;
                    if (kl > q_own) s0[r] = MASKVAL;
                    if (kl + 32 > q_own) s1[r] = MASKVAL;
                }
            }

            // ---- tree row max + pair exchange
            float t8[8];
            #pragma unroll
            for (int r = 0; r < 8; ++r)
                t8[r] = fmaxf(fmaxf(s0[r], s0[r + 8]), fmaxf(s1[r], s1[r + 8]));
            #pragma unroll
            for (int r = 0; r < 4; ++r) t8[r] = fmaxf(t8[r], t8[r + 4]);
            float pm = fmaxf(fmaxf(t8[0], t8[1]), fmaxf(t8[2], t8[3]));
            pm = fmaxf(pm, __shfl_xor(pm, 32));

            // ---- defer-max rescale (T13)
            if (__any(pm > mrow + DEFER_TH)) {
                const float mnew = fmaxf(mrow, pm);
                const float alpha = ex2(mrow - mnew);
                #pragma unroll
                for (int r = 0; r < 16; ++r) { y0[r] *= alpha; y1[r] *= alpha; }
                lrow *= alpha;
                mrow = mnew;
            }
            // ---- exp2 + tree row sum
            #pragma unroll
            for (int r = 0; r < 16; ++r) {
                s0[r] = ex2(s0[r] - mrow);
                s1[r] = ex2(s1[r] - mrow);
            }
            float a8[8];
            #pragma unroll
            for (int r = 0; r < 8; ++r) a8[r] = (s0[r] + s0[r + 8]) + (s1[r] + s1[r + 8]);
            #pragma unroll
            for (int r = 0; r < 4; ++r) a8[r] += a8[r + 4];
            float sum = (a8[0] + a8[1]) + (a8[2] + a8[3]);
            sum += __shfl_xor(sum, 32);
            lrow += sum;

            // ---- Y^T += V^T P^T (8 mfma); P^T frags via cvt_pk+permlane32_swap
            PV_STEP(0, s0, 0)
            PV_STEP(1, s0, 8)
            PV_STEP(2, s1, 0)
            PV_STEP(3, s1, 8)
        }

        // ---- epilogue: normalize, transpose via per-wave LDS, coalesced store
        {
            const float inv = 1.f / lrow;
            char* ysb = (char*)&Ysc[wid][0];
            #pragma unroll
            for (int t = 0; t < 8; ++t) {
                const int dl = ((2 * t) & 3) + 8 * (t >> 1) + 4 * hi;
                unsigned int wa = cvtpk(y0[2 * t] * inv, y0[2 * t + 1] * inv);
                unsigned int wb = cvtpk(y1[2 * t] * inv, y1[2 * t + 1] * inv);
                *reinterpret_cast<unsigned int*>(ysb + lq * 144 + dl * 2) = wa;
                *reinterpret_cast<unsigned int*>(ysb + lq * 144 + (dl + 32) * 2) = wb;
            }
            #pragma unroll
            for (int u = 0; u < 4; ++u) {
                const int rr = lane >> 1, ch = (lane & 1) + 2 * u;
                uint4 val = *reinterpret_cast<const uint4*>(ysb + rr * 144 + ch * 16);
                *reinterpret_cast<uint4*>(Yb + (rowbase + q0 + wid * 32 + rr) * CDIM + h * DHEAD + ch * 8) = val;
            }
        }
    }
}

// ---------------------------------------------------------------------------
extern "C" void kernel_launch(void* const* d_in, const int* in_sizes, int n_in,
                              void* d_out, int out_size, void* d_ws, size_t ws_size,
                              hipStream_t stream)
{
    const float* x  = (const float*)d_in[0];
    const float* Wk = (const float*)d_in[1];
    const float* bk = (const float*)d_in[2];
    const float* Wq = (const float*)d_in[3];
    const float* bq = (const float*)d_in[4];
    const float* Wv = (const float*)d_in[5];
    const float* bv = (const float*)d_in[6];
    const float* Wp = (const float*)d_in[7];
    const float* bp = (const float*)d_in[8];

    const size_t xe = (size_t)MROWS * CDIM;   // 8,388,608
    const size_t we = (size_t)CDIM * CDIM;    // 1,048,576
    unsigned short* xb    = (unsigned short*)d_ws;
    unsigned short* wqkvt = xb + xe;          // [3072][1024] = Wq^T|Wk^T|Wv^T
    unsigned short* wpt   = wqkvt + 3 * we;
    unsigned short* qkv   = wpt + we;         // [8192][3072] bf16
    unsigned short* ab    = qkv + (size_t)MROWS * QSTR;
    float*          bias3 = (float*)(ab + xe);

    cvt_x_kernel<<<(int)(xe / 8 / 256), 256, 0, stream>>>(x, xb);
    wt_kernel<<<dim3(32, 32, 4), 256, 0, stream>>>(
        Wq, Wk, Wv, Wp, wqkvt, wqkvt + we, wqkvt + 2 * we, wpt);
    pack_bias<<<12, 256, 0, stream>>>(bq, bk, bv, bias3);

    // fused QKV projection: [8192,1024] @ [1024,3072] + bias (q cols scaled)
    gemm_glds<0><<<24 * 64, 256, 0, stream>>>(xb, wqkvt, bias3, qkv,
                                              MROWS, QSTR, CDIM, 1024);

    attn_mfma6<<<512, 256, 0, stream>>>(qkv, ab);

    // output projection -> fp32
    gemm_glds<1><<<8 * 64, 256, 0, stream>>>(ab, wpt, bp, d_out,
                                             MROWS, CDIM, CDIM, 0);
}

// Round 10
// 169.026 us; speedup vs baseline: 1.1614x; 1.0045x over previous
//
#include <hip/hip_runtime.h>
#include <hip/hip_bf16.h>

#define CDIM   1024
#define NHEADS 16
#define DHEAD  64
#define BATCH  4
#define TSEQ   2048
#define MROWS  (BATCH * TSEQ)
#define QSTR   3072                /* fused qkv row stride */
#define NEG_BIG (-1e30f)
#define MASKVAL (-3.0e38f)
#define SCALE_L2E 0.18033688011f   /* 0.125 * log2(e) */
#define DEFER_TH 11.5416f          /* 8 nats in log2 units */

typedef __attribute__((ext_vector_type(8)))  short bf16x8;
typedef __attribute__((ext_vector_type(4)))  float f32x4;
typedef __attribute__((ext_vector_type(16))) float f32x16;

__device__ __forceinline__ unsigned short f2bf(float f) {
    __hip_bfloat16 h = __float2bfloat16(f);
    return *reinterpret_cast<unsigned short*>(&h);
}
__device__ __forceinline__ unsigned int cvtpk(float a, float b) {
    unsigned r;
    asm("v_cvt_pk_bf16_f32 %0, %1, %2" : "=v"(r) : "v"(a), "v"(b));
    return r;   // lo = bf16(a), hi = bf16(b)
}
__device__ __forceinline__ float ex2(float x) {   // raw v_exp_f32 (exp2)
    float r; asm("v_exp_f32 %0, %1" : "=v"(r) : "v"(x)); return r;
}

// ---------------- x: fp32 -> bf16 (8 elems/thread) --------------------------
__global__ __launch_bounds__(256)
void cvt_x_kernel(const float* __restrict__ in, unsigned short* __restrict__ out)
{
    size_t i = (size_t)blockIdx.x * 256 + threadIdx.x;
    const float4* p = reinterpret_cast<const float4*>(in) + i * 2;
    float4 a = p[0], b = p[1];
    uint4 o;
    o.x = (unsigned)f2bf(a.x) | ((unsigned)f2bf(a.y) << 16);
    o.y = (unsigned)f2bf(a.z) | ((unsigned)f2bf(a.w) << 16);
    o.z = (unsigned)f2bf(b.x) | ((unsigned)f2bf(b.y) << 16);
    o.w = (unsigned)f2bf(b.z) | ((unsigned)f2bf(b.w) << 16);
    *reinterpret_cast<uint4*>(out + i * 8) = o;
}

// ---------------- W[K][N] fp32 -> W^T[N][K] bf16 (32x32 LDS tiles) ----------
__global__ __launch_bounds__(256)
void wt_kernel(const float* __restrict__ W0, const float* __restrict__ W1,
               const float* __restrict__ W2, const float* __restrict__ W3,
               unsigned short* __restrict__ T0, unsigned short* __restrict__ T1,
               unsigned short* __restrict__ T2, unsigned short* __restrict__ T3)
{
    const float* W; unsigned short* T;
    switch (blockIdx.z) {
        case 0:  W = W0; T = T0; break;
        case 1:  W = W1; T = T1; break;
        case 2:  W = W2; T = T2; break;
        default: W = W3; T = T3; break;
    }
    __shared__ float tile[32][33];
    const int t = threadIdx.x;
    const int r = t >> 3;
    const int c4 = (t & 7) * 4;
    const int n0 = blockIdx.x * 32, k0 = blockIdx.y * 32;
    float4 v = *reinterpret_cast<const float4*>(&W[(size_t)(k0 + r) * CDIM + n0 + c4]);
    tile[r][c4 + 0] = v.x; tile[r][c4 + 1] = v.y;
    tile[r][c4 + 2] = v.z; tile[r][c4 + 3] = v.w;
    __syncthreads();
    uint2 o;
    o.x = (unsigned)f2bf(tile[c4 + 0][r]) | ((unsigned)f2bf(tile[c4 + 1][r]) << 16);
    o.y = (unsigned)f2bf(tile[c4 + 2][r]) | ((unsigned)f2bf(tile[c4 + 3][r]) << 16);
    *reinterpret_cast<uint2*>(&T[(size_t)(n0 + r) * CDIM + k0 + c4]) = o;
}

// ---------------- bias concat [bq|bk|bv] ------------------------------------
__global__ __launch_bounds__(256)
void pack_bias(const float* __restrict__ bq, const float* __restrict__ bk,
               const float* __restrict__ bv, float* __restrict__ o)
{
    int i = blockIdx.x * 256 + threadIdx.x;   // 0..3071
    float v = (i < 1024) ? bq[i] : (i < 2048 ? bk[i - 1024] : bv[i - 2048]);
    o[i] = v;
}

// ================= 8-phase 256x256 deep-pipelined GEMM (T2+T3+T4+T5) ========
// 512 thr = 8 waves (2M x 4N), per-wave C = 128x64. BK=64 per K-tile, K=1024
// -> 16 K-tiles, 8 iterations x 2 tiles. LDS 128KB: 2 bufs x {A-lo,A-hi,B-lo,
// B-hi} halves of 16KB. Per phase: {ds_read frags | stage 1 half-tile} ->
// raw barrier -> lgkmcnt(0) -> setprio(1) 16 MFMA setprio(0) -> [vmcnt] ->
// barrier. Counted vmcnt(4) at phases 4/8 (queue=12, drain 8 needed, keep 4);
// tail uses vmcnt(0) when stages were skipped (queue depth changes).
// Stage order phi1..8: A-lo/hi(2i+1)->buf1, B-lo/hi(2i+2)->buf0,
// A-lo/hi(2i+2)->buf0, B-lo/hi(2i+3)->buf1. Consumption: B(t) done by phase 2
// of tile t, A(t) by phase 3 => every WAR separated by >=1 barrier.
// glds: linear LDS dest (wave base + lane*16), inverse-swizzled global source
// granule g = (lane&7)^(lane>>3 &7); reads use slot (k*4+lg)^(lj&7).

#define GBAR8  asm volatile("s_barrier" ::: "memory")
#define LGKM0  asm volatile("s_waitcnt lgkmcnt(0)" ::: "memory")
#define VMC4   asm volatile("s_waitcnt vmcnt(4)" ::: "memory")
#define VMC0   asm volatile("s_waitcnt vmcnt(0)" ::: "memory")

#define STAGE8(dsthalf, srcp) do { \
    __builtin_amdgcn_global_load_lds( \
        (const __attribute__((address_space(1))) void*)(srcp), \
        (__attribute__((address_space(3))) void*)((dsthalf) + wv * 1024), 16, 0, 0); \
    __builtin_amdgcn_global_load_lds( \
        (const __attribute__((address_space(1))) void*)((srcp) + 65536), \
        (__attribute__((address_space(3))) void*)((dsthalf) + 8192 + wv * 1024), 16, 0, 0); \
} while (0)

#define LDA8(grp) do { \
    _Pragma("unroll") for (int m_ = 0; m_ < 4; ++m_) { \
        const int rl_ = (grp) * 64 + m_ * 16 + lj; \
        _Pragma("unroll") for (int k_ = 0; k_ < 2; ++k_) \
            af[m_][k_] = *reinterpret_cast<const bf16x8*>( \
                Ab + rl_ * 128 + (((k_ * 4 + lg) ^ (lj & 7)) * 16)); \
    } } while (0)

#define LDB8(pairi) do { \
    _Pragma("unroll") for (int n_ = 0; n_ < 2; ++n_) { \
        const int nr_ = (pairi) * 2 + n_; \
        const int rl_ = (wc & 1) * 64 + nr_ * 16 + lj; \
        _Pragma("unroll") for (int k_ = 0; k_ < 2; ++k_) \
            bfr[nr_][k_] = *reinterpret_cast<const bf16x8*>( \
                Bb + rl_ * 128 + (((k_ * 4 + lg) ^ (lj & 7)) * 16)); \
    } } while (0)

#define MM8(mg, npair) do { \
    __builtin_amdgcn_s_setprio(1); \
    _Pragma("unroll") for (int m_ = 0; m_ < 4; ++m_) \
        _Pragma("unroll") for (int n_ = 0; n_ < 2; ++n_) \
            _Pragma("unroll") for (int k_ = 0; k_ < 2; ++k_) \
                acc[(mg) * 4 + m_][(npair) * 2 + n_] = \
                    __builtin_amdgcn_mfma_f32_16x16x32_bf16( \
                        af[m_][k_], bfr[(npair) * 2 + n_][k_], \
                        acc[(mg) * 4 + m_][(npair) * 2 + n_], 0, 0, 0); \
    __builtin_amdgcn_s_setprio(0); \
} while (0)

__global__ __launch_bounds__(512)
void gemm_8ph(const unsigned short* __restrict__ A,
              const unsigned short* __restrict__ BT,
              const float* __restrict__ bias,
              unsigned short* __restrict__ Cout, int N, int nScaled)
{
    __shared__ __align__(16) char lds8[2][65536];
    const int tid = threadIdx.x;
    const int nbn = N >> 8;
    const int bid = blockIdx.x;
    const int wg  = (bid & 7) * ((int)gridDim.x >> 3) + (bid >> 3);  // XCD swizzle
    const int n0  = (wg % nbn) * 256;
    const int m0  = (wg / nbn) * 256;

    const int lane = tid & 63, wv = tid >> 6;
    const int wr = wv >> 2, wc = wv & 3;
    const int lj = lane & 15, lg = lane >> 4;
    const int srow = tid >> 3;                              // 0..63
    const int gsw  = 8 * ((tid & 7) ^ ((tid >> 3) & 7));    // src granule (elems)

    char* buf0 = &lds8[0][0];
    char* buf1 = &lds8[1][0];

    // stage source row pointers (per-thread, K=1024 row stride)
    const unsigned short* Alo = A  + (size_t)(m0 + srow) * 1024 + gsw;
    const unsigned short* Ahi = A  + (size_t)(m0 + 128 + srow) * 1024 + gsw;
    const unsigned short* Blo = BT + (size_t)(n0 + srow) * 1024 + gsw;
    const unsigned short* Bhi = BT + (size_t)(n0 + 128 + srow) * 1024 + gsw;

    f32x4 acc[8][4];
    #pragma unroll
    for (int i = 0; i < 8; ++i)
        #pragma unroll
        for (int j = 0; j < 4; ++j) acc[i][j] = f32x4{0.f, 0.f, 0.f, 0.f};

    // ---- prologue: A(0),B(0) -> buf0; B(1) -> buf1
    STAGE8(buf0 + 0,     Alo);
    STAGE8(buf0 + 16384, Ahi);
    STAGE8(buf0 + 32768, Blo);
    STAGE8(buf0 + 49152, Bhi);
    STAGE8(buf1 + 32768, Blo + 64);
    STAGE8(buf1 + 49152, Bhi + 64);
    VMC0; GBAR8;

    bf16x8 af[4][2], bfr[4][2];

    for (int it = 0; it < 8; ++it) {
        const int e = 2 * it, o = e + 1;
        const bool se = (e + 2) < 16;     // stage tile e+2?
        const bool so = (o + 2) < 16;     // stage tile o+2?

        // ===== K-tile e (buf0) =====
        char* Ab = buf0 + wr * 16384;
        char* Bb = buf0 + 32768 + (wc >> 1) * 16384;
        // phase 1: A m0-3, B n0-1 | stage A-lo(o)->buf1
        LDA8(0); LDB8(0);
        STAGE8(buf1 + 0, Alo + o * 64);
        GBAR8; LGKM0; MM8(0, 0); GBAR8;
        // phase 2: B n2-3 | stage A-hi(o)->buf1
        LDB8(1);
        STAGE8(buf1 + 16384, Ahi + o * 64);
        GBAR8; LGKM0; MM8(0, 1); GBAR8;
        // phase 3: A m4-7 | stage B-lo(e+2)->buf0
        LDA8(1);
        if (se) STAGE8(buf0 + 32768, Blo + (e + 2) * 64);
        GBAR8; LGKM0; MM8(1, 0); GBAR8;
        // phase 4: stage B-hi(e+2)->buf0 | counted vmcnt
        if (se) STAGE8(buf0 + 49152, Bhi + (e + 2) * 64);
        GBAR8; LGKM0; MM8(1, 1);
        if (se) { VMC4; } else { VMC0; }
        GBAR8;

        // ===== K-tile o (buf1) =====
        Ab = buf1 + wr * 16384;
        Bb = buf1 + 32768 + (wc >> 1) * 16384;
        // phase 5: A m0-3, B n0-1 | stage A-lo(e+2)->buf0
        LDA8(0); LDB8(0);
        if (se) STAGE8(buf0 + 0, Alo + (e + 2) * 64);
        GBAR8; LGKM0; MM8(0, 0); GBAR8;
        // phase 6: B n2-3 | stage A-hi(e+2)->buf0
        LDB8(1);
        if (se) STAGE8(buf0 + 16384, Ahi + (e + 2) * 64);
        GBAR8; LGKM0; MM8(0, 1); GBAR8;
        // phase 7: A m4-7 | stage B-lo(o+2)->buf1
        LDA8(1);
        if (so) STAGE8(buf1 + 32768, Blo + (o + 2) * 64);
        GBAR8; LGKM0; MM8(1, 0); GBAR8;
        // phase 8: stage B-hi(o+2)->buf1 | counted vmcnt
        if (so) STAGE8(buf1 + 49152, Bhi + (o + 2) * 64);
        GBAR8; LGKM0; MM8(1, 1);
        if (so) { VMC4; } else { VMC0; }
        GBAR8;
    }

    // ---- epilogue: bias + optional scale, bf16 store
    const float sc = (n0 < nScaled) ? SCALE_L2E : 1.0f;
    float bcol[4];
    #pragma unroll
    for (int nr = 0; nr < 4; ++nr) bcol[nr] = bias[n0 + wc * 64 + nr * 16 + lj];

    #pragma unroll
    for (int mr = 0; mr < 8; ++mr) {
        #pragma unroll
        for (int r4 = 0; r4 < 4; ++r4) {
            const int row = m0 + wr * 128 + mr * 16 + lg * 4 + r4;
            #pragma unroll
            for (int nr = 0; nr < 4; ++nr) {
                const int col = n0 + wc * 64 + nr * 16 + lj;
                Cout[(size_t)row * N + col] = f2bf((acc[mr][nr][r4] + bcol[nr]) * sc);
            }
        }
    }
}

// ---------------- m97-structure GEMM, BK=64 (P-projection: N=1024 shape -----
// is a poor fit for 256^2 tiles -> keep verified 128^2 kernel, 512 blocks)
template<int OUTMODE>
__global__ __launch_bounds__(256)
void gemm_glds(const unsigned short* __restrict__ A,
               const unsigned short* __restrict__ BT,
               const float* __restrict__ bias,
               void* __restrict__ Cout, int M, int N, int K, int nScaled)
{
    __shared__ __align__(16) unsigned short As[128 * 64];   // 16KB
    __shared__ __align__(16) unsigned short Bs[128 * 64];
    const int tid = threadIdx.x;
    const int nbn = N >> 7;
    const int bid = blockIdx.x;
    const int wg  = (bid & 7) * ((int)gridDim.x >> 3) + (bid >> 3);  // XCD swizzle
    const int n0  = (wg % nbn) * 128;
    const int m0  = (wg / nbn) * 128;

    const int lane = tid & 63, w = tid >> 6;
    const int wr = w >> 1, wc = w & 1;
    const int lj = lane & 15, lg = lane >> 4;
    const int srow = w * 8 + (lane >> 3);               // row within 32-row round
    const int gsw  = 8 * ((lane & 7) ^ (lane >> 3));    // src granule (elements)

    char* AsB = (char*)As;
    char* BsB = (char*)Bs;

    f32x4 acc[4][4];
    #pragma unroll
    for (int i = 0; i < 4; ++i)
        #pragma unroll
        for (int j = 0; j < 4; ++j) acc[i][j] = f32x4{0.f, 0.f, 0.f, 0.f};

    for (int k0 = 0; k0 < K; k0 += 64) {
        __syncthreads();
        #pragma unroll
        for (int ra = 0; ra < 4; ++ra) {
            const int r = ra * 32 + srow;
            __builtin_amdgcn_global_load_lds(
                (const __attribute__((address_space(1))) void*)(A + (size_t)(m0 + r) * K + k0 + gsw),
                (__attribute__((address_space(3))) void*)(AsB + ra * 4096 + w * 1024),
                16, 0, 0);
            __builtin_amdgcn_global_load_lds(
                (const __attribute__((address_space(1))) void*)(BT + (size_t)(n0 + r) * K + k0 + gsw),
                (__attribute__((address_space(3))) void*)(BsB + ra * 4096 + w * 1024),
                16, 0, 0);
        }
        __syncthreads();
        #pragma unroll
        for (int ks = 0; ks < 2; ++ks) {
            bf16x8 af[4], bfr[4];
            #pragma unroll
            for (int i = 0; i < 4; ++i) {
                const int r = wr * 64 + i * 16 + lj;
                af[i] = *reinterpret_cast<const bf16x8*>(
                    AsB + r * 128 + (((ks * 4 + lg) ^ (lj & 7)) * 16));
            }
            #pragma unroll
            for (int j = 0; j < 4; ++j) {
                const int r = wc * 64 + j * 16 + lj;
                bfr[j] = *reinterpret_cast<const bf16x8*>(
                    BsB + r * 128 + (((ks * 4 + lg) ^ (lj & 7)) * 16));
            }
            #pragma unroll
            for (int i = 0; i < 4; ++i)
                #pragma unroll
                for (int j = 0; j < 4; ++j)
                    acc[i][j] = __builtin_amdgcn_mfma_f32_16x16x32_bf16(af[i], bfr[j], acc[i][j], 0, 0, 0);
        }
    }

    const float sc = (n0 < nScaled) ? SCALE_L2E : 1.0f;
    float bcol[4];
    #pragma unroll
    for (int j = 0; j < 4; ++j) bcol[j] = bias[n0 + wc * 64 + j * 16 + lj];

    #pragma unroll
    for (int i = 0; i < 4; ++i) {
        #pragma unroll
        for (int r4 = 0; r4 < 4; ++r4) {
            const int row = m0 + wr * 64 + i * 16 + lg * 4 + r4;
            #pragma unroll
            for (int j = 0; j < 4; ++j) {
                const int col = n0 + wc * 64 + j * 16 + lj;
                float v = (acc[i][j][r4] + bcol[j]) * sc;
                if (OUTMODE == 0)
                    reinterpret_cast<unsigned short*>(Cout)[(size_t)row * N + col] = f2bf(v);
                else
                    reinterpret_cast<float*>(Cout)[(size_t)row * N + col] = v;
            }
        }
    }
}

// ---------------- MFMA flash attention (R7/R9-verified: 79us, VGPR 124) -----
// DO NOT add __launch_bounds__ min-waves: R8's (512,4) variant spilled.
#define PV_STEP(m, T, rb) { \
    unsigned int w01 = cvtpk(T[(rb)+0], T[(rb)+1]); \
    unsigned int w23 = cvtpk(T[(rb)+2], T[(rb)+3]); \
    unsigned int w45 = cvtpk(T[(rb)+4], T[(rb)+5]); \
    unsigned int w67 = cvtpk(T[(rb)+6], T[(rb)+7]); \
    asm("v_permlane32_swap_b32 %0, %1" : "+v"(w01), "+v"(w45)); \
    asm("v_permlane32_swap_b32 %0, %1" : "+v"(w23), "+v"(w67)); \
    union { unsigned int u[4]; bf16x8 v; } pa; \
    pa.u[0] = w01; pa.u[1] = w23; pa.u[2] = w45; pa.u[3] = w67; \
    const int voff = (32 * (m) + 16 * hi) ^ lqswz; \
    bf16x8 va = *reinterpret_cast<const bf16x8*>(VTB + lq * 128 + voff); \
    bf16x8 vb = *reinterpret_cast<const bf16x8*>(VTB + (lq + 32) * 128 + voff); \
    y0 = __builtin_amdgcn_mfma_f32_32x32x16_bf16(va, pa.v, y0, 0, 0, 0); \
    y1 = __builtin_amdgcn_mfma_f32_32x32x16_bf16(vb, pa.v, y1, 0, 0, 0); \
}

__global__ __launch_bounds__(256)
void attn_mfma6(const unsigned short* __restrict__ QKV, unsigned short* __restrict__ Yb)
{
    __shared__ unsigned short Ks[64 * 64];    // [key][d], swizzled
    __shared__ unsigned short VTs[64 * 64];   // [d][key], swizzled
    __shared__ unsigned short Ysc[4][32 * 72];// per-wave [q][d], 144B stride

    const int tid = threadIdx.x, lane = tid & 63, wid = tid >> 6;
    const int lq = lane & 31, hi = lane >> 5;
    const int lqswz = (lq & 7) << 4;

    // XCD-grouped decomposition: id%8 == hb%8 -> same (h,b) shares an XCD
    const int id  = blockIdx.x;
    const int kk  = id >> 3;
    const int hb  = (id & 7) + 8 * (kk >> 3);
    const int pair = kk & 7;
    const int h = hb & 15, bz = hb >> 4;

    const size_t rowbase = (size_t)bz * TSEQ;
    const int hq = h * DHEAD, hk = 1024 + h * DHEAD, hv = 2048 + h * DHEAD;
    char* KsB = (char*)Ks;
    char* VTB = (char*)VTs;

    // staging thread mapping (constant per thread)
    const int krow = tid >> 3;           // K rows krow, krow+32
    const int kswz = ((tid & 7) * 16) ^ ((krow & 7) << 4);
    const int vk2  = 2 * (tid & 31);     // V key-pair
    const int vdg  = (tid >> 5) * 8;     // V d-group
    const int vkb  = vk2 * 2;            // byte offset of pair

    for (int iter = 0; iter < 2; ++iter) {
        const int qtile = iter ? (15 - pair) : pair;
        const int q0 = qtile * 128;
        const int wq = q0 + wid * 32;

        bf16x8 qf[4];                            // Q^T B-frags: d = 16s + 8hi + j
        {
            const unsigned short* qp = QKV + (rowbase + wq + lq) * QSTR + hq + hi * 8;
            #pragma unroll
            for (int s = 0; s < 4; ++s)
                qf[s] = *reinterpret_cast<const bf16x8*>(qp + s * 16);
        }
        f32x16 y0, y1;                           // Y^T tiles: d 0..31 / 32..63
        #pragma unroll
        for (int r = 0; r < 16; ++r) { y0[r] = 0.f; y1[r] = 0.f; }
        float mrow = NEG_BIG, lrow = 0.f;

        const int ktend = 2 * qtile + 2;

        // prefetch tile 0 into registers
        uint4 kr0, kr1, vr0, vr1;
        {
            const unsigned short* kp = QKV + (rowbase + krow) * QSTR + hk + (tid & 7) * 8;
            kr0 = *reinterpret_cast<const uint4*>(kp);
            kr1 = *reinterpret_cast<const uint4*>(kp + 32 * QSTR);
            const unsigned short* vp = QKV + (rowbase + vk2) * QSTR + hv + vdg;
            vr0 = *reinterpret_cast<const uint4*>(vp);
            vr1 = *reinterpret_cast<const uint4*>(vp + QSTR);
        }

        for (int kt = 0; kt < ktend; ++kt) {
            __syncthreads();                     // previous tile's consumers done
            // ---- write prefetched regs -> LDS (K swizzled, V^T perm-packed)
            *reinterpret_cast<uint4*>(KsB + krow * 128 + kswz) = kr0;
            *reinterpret_cast<uint4*>(KsB + (krow + 32) * 128 + kswz) = kr1;
            {
                unsigned pe, po;
                pe = __builtin_amdgcn_perm(vr1.x, vr0.x, 0x05040100u);
                po = __builtin_amdgcn_perm(vr1.x, vr0.x, 0x07060302u);
                *reinterpret_cast<unsigned*>(VTB + (vdg + 0) * 128 + (vkb ^ 0x00)) = pe;
                *reinterpret_cast<unsigned*>(VTB + (vdg + 1) * 128 + (vkb ^ 0x10)) = po;
                pe = __builtin_amdgcn_perm(vr1.y, vr0.y, 0x05040100u);
                po = __builtin_amdgcn_perm(vr1.y, vr0.y, 0x07060302u);
                *reinterpret_cast<unsigned*>(VTB + (vdg + 2) * 128 + (vkb ^ 0x20)) = pe;
                *reinterpret_cast<unsigned*>(VTB + (vdg + 3) * 128 + (vkb ^ 0x30)) = po;
                pe = __builtin_amdgcn_perm(vr1.z, vr0.z, 0x05040100u);
                po = __builtin_amdgcn_perm(vr1.z, vr0.z, 0x07060302u);
                *reinterpret_cast<unsigned*>(VTB + (vdg + 4) * 128 + (vkb ^ 0x40)) = pe;
                *reinterpret_cast<unsigned*>(VTB + (vdg + 5) * 128 + (vkb ^ 0x50)) = po;
                pe = __builtin_amdgcn_perm(vr1.w, vr0.w, 0x05040100u);
                po = __builtin_amdgcn_perm(vr1.w, vr0.w, 0x07060302u);
                *reinterpret_cast<unsigned*>(VTB + (vdg + 6) * 128 + (vkb ^ 0x60)) = pe;
                *reinterpret_cast<unsigned*>(VTB + (vdg + 7) * 128 + (vkb ^ 0x70)) = po;
            }
            __syncthreads();                     // LDS tile ready

            // ---- issue next tile's global loads (latency hides under compute)
            if (kt + 1 < ktend) {
                const unsigned short* kp = QKV + (rowbase + (kt + 1) * 64 + krow) * QSTR + hk + (tid & 7) * 8;
                kr0 = *reinterpret_cast<const uint4*>(kp);
                kr1 = *reinterpret_cast<const uint4*>(kp + 32 * QSTR);
                const unsigned short* vp = QKV + (rowbase + (kt + 1) * 64 + vk2) * QSTR + hv + vdg;
                vr0 = *reinterpret_cast<const uint4*>(vp);
                vr1 = *reinterpret_cast<const uint4*>(vp + QSTR);
            }

            if (kt * 64 > wq + 31) continue;     // tile above diagonal for this wave

            // ---- S^T = K Q^T (8 mfma 32x32x16); scale pre-folded into Q
            f32x16 s0, s1;
            #pragma unroll
            for (int r = 0; r < 16; ++r) { s0[r] = 0.f; s1[r] = 0.f; }
            #pragma unroll
            for (int s = 0; s < 4; ++s) {
                const int off = (s * 32 + hi * 16) ^ lqswz;
                bf16x8 k0 = *reinterpret_cast<const bf16x8*>(KsB + lq * 128 + off);
                bf16x8 k1 = *reinterpret_cast<const bf16x8*>(KsB + (lq + 32) * 128 + off);
                s0 = __builtin_amdgcn_mfma_f32_32x32x16_bf16(k0, qf[s], s0, 0, 0, 0);
                s1 = __builtin_amdgcn_mfma_f32_32x32x16_bf16(k1, qf[s], s1, 0, 0, 0);
            }

            // ---- causal mask (diagonal tiles only)
            const bool diag = (kt * 64 + 63) > wq;
            if (diag) {
                const int q_own = wq + lq;
                #pragma unroll
                for (int r = 0; r < 16; ++r) {
                    const int kl = kt * 64 + (r & 3) + 8 * (r >> 2) + 4 * hi;
                    if (kl > q_own) s0[r] = MASKVAL;
                    if (kl + 32 > q_own) s1[r] = MASKVAL;
                }
            }

            // ---- tree row max + pair exchange
            float t8[8];
            #pragma unroll
            for (int r = 0; r < 8; ++r)
                t8[r] = fmaxf(fmaxf(s0[r], s0[r + 8]), fmaxf(s1[r], s1[r + 8]));
            #pragma unroll
            for (int r = 0; r < 4; ++r) t8[r] = fmaxf(t8[r], t8[r + 4]);
            float pm = fmaxf(fmaxf(t8[0], t8[1]), fmaxf(t8[2], t8[3]));
            pm = fmaxf(pm, __shfl_xor(pm, 32));

            // ---- defer-max rescale (T13)
            if (__any(pm > mrow + DEFER_TH)) {
                const float mnew = fmaxf(mrow, pm);
                const float alpha = ex2(mrow - mnew);
                #pragma unroll
                for (int r = 0; r < 16; ++r) { y0[r] *= alpha; y1[r] *= alpha; }
                lrow *= alpha;
                mrow = mnew;
            }
            // ---- exp2 + tree row sum
            #pragma unroll
            for (int r = 0; r < 16; ++r) {
                s0[r] = ex2(s0[r] - mrow);
                s1[r] = ex2(s1[r] - mrow);
            }
            float a8[8];
            #pragma unroll
            for (int r = 0; r < 8; ++r) a8[r] = (s0[r] + s0[r + 8]) + (s1[r] + s1[r + 8]);
            #pragma unroll
            for (int r = 0; r < 4; ++r) a8[r] += a8[r + 4];
            float sum = (a8[0] + a8[1]) + (a8[2] + a8[3]);
            sum += __shfl_xor(sum, 32);
            lrow += sum;

            // ---- Y^T += V^T P^T (8 mfma); P^T frags via cvt_pk+permlane32_swap
            PV_STEP(0, s0, 0)
            PV_STEP(1, s0, 8)
            PV_STEP(2, s1, 0)
            PV_STEP(3, s1, 8)
        }

        // ---- epilogue: normalize, transpose via per-wave LDS, coalesced store
        {
            const float inv = 1.f / lrow;
            char* ysb = (char*)&Ysc[wid][0];
            #pragma unroll
            for (int t = 0; t < 8; ++t) {
                const int dl = ((2 * t) & 3) + 8 * (t >> 1) + 4 * hi;
                unsigned int wa = cvtpk(y0[2 * t] * inv, y0[2 * t + 1] * inv);
                unsigned int wb = cvtpk(y1[2 * t] * inv, y1[2 * t + 1] * inv);
                *reinterpret_cast<unsigned int*>(ysb + lq * 144 + dl * 2) = wa;
                *reinterpret_cast<unsigned int*>(ysb + lq * 144 + (dl + 32) * 2) = wb;
            }
            #pragma unroll
            for (int u = 0; u < 4; ++u) {
                const int rr = lane >> 1, ch = (lane & 1) + 2 * u;
                uint4 val = *reinterpret_cast<const uint4*>(ysb + rr * 144 + ch * 16);
                *reinterpret_cast<uint4*>(Yb + (rowbase + q0 + wid * 32 + rr) * CDIM + h * DHEAD + ch * 8) = val;
            }
        }
    }
}

// ---------------------------------------------------------------------------
extern "C" void kernel_launch(void* const* d_in, const int* in_sizes, int n_in,
                              void* d_out, int out_size, void* d_ws, size_t ws_size,
                              hipStream_t stream)
{
    const float* x  = (const float*)d_in[0];
    const float* Wk = (const float*)d_in[1];
    const float* bk = (const float*)d_in[2];
    const float* Wq = (const float*)d_in[3];
    const float* bq = (const float*)d_in[4];
    const float* Wv = (const float*)d_in[5];
    const float* bv = (const float*)d_in[6];
    const float* Wp = (const float*)d_in[7];
    const float* bp = (const float*)d_in[8];

    const size_t xe = (size_t)MROWS * CDIM;   // 8,388,608
    const size_t we = (size_t)CDIM * CDIM;    // 1,048,576
    unsigned short* xb    = (unsigned short*)d_ws;
    unsigned short* wqkvt = xb + xe;          // [3072][1024] = Wq^T|Wk^T|Wv^T
    unsigned short* wpt   = wqkvt + 3 * we;
    unsigned short* qkv   = wpt + we;         // [8192][3072] bf16
    unsigned short* ab    = qkv + (size_t)MROWS * QSTR;
    float*          bias3 = (float*)(ab + xe);

    cvt_x_kernel<<<(int)(xe / 8 / 256), 256, 0, stream>>>(x, xb);
    wt_kernel<<<dim3(32, 32, 4), 256, 0, stream>>>(
        Wq, Wk, Wv, Wp, wqkvt, wqkvt + we, wqkvt + 2 * we, wpt);
    pack_bias<<<12, 256, 0, stream>>>(bq, bk, bv, bias3);

    // fused QKV projection: 8-phase 256^2 pipeline, 32x12 = 384 blocks
    gemm_8ph<<<32 * 12, 512, 0, stream>>>(xb, wqkvt, bias3, qkv, QSTR, 1024);

    attn_mfma6<<<512, 256, 0, stream>>>(qkv, ab);

    // output projection -> fp32 (128^2 kernel: N=1024 shape, 512 blocks)
    gemm_glds<1><<<8 * 64, 256, 0, stream>>>(ab, wpt, bp, d_out,
                                             MROWS, CDIM, CDIM, 0);
}